// Round 4
// baseline (92.143 us; speedup 1.0000x reference)
//
#include <hip/hip_runtime.h>

// StaticKVCache steady-state step: ring write + roll + concat as a pure
// permutation-copy gather. Each block handles RPB consecutive output rows,
// both K and V -> 2*RPB independent 16B load/store chains per thread for
// deep memory-level parallelism. Nontemporal hints: every byte is touched
// exactly once, so cache retention is pure pollution.
//
// Row mapping for output row t (0..15359):
//   t < SINK          -> sink row t
//   else tt = t-SINK  -> ring row r0 = (tt + new_write_idx) % LOCAL
//       d = (r0 - write_idx) mod LOCAL
//       d < NEW_LEN   -> new row d          (freshly written slot)
//       else          -> local row r0       (untouched ring slot)

constexpr int SINK    = 3 * 1024;    // 3072
constexpr int LOCAL   = 12 * 1024;   // 12288
constexpr int NEW_LEN = 1024;
constexpr int T_FULL  = SINK + LOCAL;  // 15360
constexpr int HD      = 16 * 128;      // 2048 floats per row
constexpr int ROWV4   = HD / 4;        // 512 float4 per row
constexpr int RPB     = 4;             // rows per block

// Native clang vector type: __builtin_nontemporal_* requires it.
typedef float f4 __attribute__((ext_vector_type(4)));

__global__ __launch_bounds__(ROWV4) void kv_linearize_kernel(
    const f4* __restrict__ sink_k, const f4* __restrict__ sink_v,
    const f4* __restrict__ local_k, const f4* __restrict__ local_v,
    const f4* __restrict__ new_k, const f4* __restrict__ new_v,
    const int* __restrict__ write_idx_p,
    f4* __restrict__ out)
{
    const int t0 = blockIdx.x * RPB;  // first row of this block
    const int c  = threadIdx.x;       // 0..ROWV4-1 (float4 column within row)

    // write_idx is a runtime scalar; normalize into [0, LOCAL)
    int wi = write_idx_p[0] % LOCAL;
    if (wi < 0) wi += LOCAL;
    int nwi = wi + NEW_LEN;            // new_write_idx
    if (nwi >= LOCAL) nwi -= LOCAL;

    const f4* srcK[RPB];
    const f4* srcV[RPB];

#pragma unroll
    for (int r = 0; r < RPB; ++r) {
        const int t = t0 + r;
        if (t < SINK) {
            srcK[r] = sink_k + (size_t)t * ROWV4;
            srcV[r] = sink_v + (size_t)t * ROWV4;
        } else {
            int r0 = (t - SINK) + nwi;     // roll by -new_write_idx
            if (r0 >= LOCAL) r0 -= LOCAL;
            int d = r0 - wi;               // distance into the written window
            if (d < 0) d += LOCAL;
            if (d < NEW_LEN) {
                srcK[r] = new_k + (size_t)d * ROWV4;
                srcV[r] = new_v + (size_t)d * ROWV4;
            } else {
                srcK[r] = local_k + (size_t)r0 * ROWV4;
                srcV[r] = local_v + (size_t)r0 * ROWV4;
            }
        }
    }

    // 2*RPB independent load chains, then 2*RPB stores.
    f4 vk[RPB], vv[RPB];
#pragma unroll
    for (int r = 0; r < RPB; ++r) {
        vk[r] = __builtin_nontemporal_load(srcK[r] + c);
        vv[r] = __builtin_nontemporal_load(srcV[r] + c);
    }
#pragma unroll
    for (int r = 0; r < RPB; ++r) {
        const int t = t0 + r;
        __builtin_nontemporal_store(vk[r], out + (size_t)t * ROWV4 + c);
        __builtin_nontemporal_store(vv[r], out + ((size_t)T_FULL + t) * ROWV4 + c);
    }
}

extern "C" void kernel_launch(void* const* d_in, const int* in_sizes, int n_in,
                              void* d_out, int out_size, void* d_ws, size_t ws_size,
                              hipStream_t stream) {
    const f4* sink_k  = (const f4*)d_in[0];
    const f4* sink_v  = (const f4*)d_in[1];
    const f4* local_k = (const f4*)d_in[2];
    const f4* local_v = (const f4*)d_in[3];
    const f4* new_k   = (const f4*)d_in[4];
    const f4* new_v   = (const f4*)d_in[5];
    const int*  widx  = (const int*)d_in[6];
    f4*         out   = (f4*)d_out;

    dim3 grid(T_FULL / RPB);
    dim3 block(ROWV4);
    kv_linearize_kernel<<<grid, block, 0, stream>>>(
        sink_k, sink_v, local_k, local_v, new_k, new_v, widx, out);
}

// Round 5
// 90.830 us; speedup vs baseline: 1.0144x; 1.0144x over previous
//
#include <hip/hip_runtime.h>

// StaticKVCache steady-state step: ring write + roll + concat as a pure
// permutation-copy gather. Persistent grid-stride form (copy-bench shape,
// G11): 2048 blocks x 256 threads, each thread walks flat f4 indices with
// stride grid*block; every iteration moves one K f4 + one V f4 (2 chains).
// 15360*512 = 7,864,320 f4 / 524,288 threads = exactly 15 iters, no tail.
//
// Row mapping for output row t (0..15359):
//   t < SINK          -> sink row t
//   else tt = t-SINK  -> ring row r0 = (tt + new_write_idx) % LOCAL
//       d = (r0 - write_idx) mod LOCAL
//       d < NEW_LEN   -> new row d          (freshly written slot)
//       else          -> local row r0       (untouched ring slot)

constexpr int SINK    = 3 * 1024;    // 3072
constexpr int LOCAL   = 12 * 1024;   // 12288
constexpr int NEW_LEN = 1024;
constexpr int T_FULL  = SINK + LOCAL;  // 15360
constexpr int HD      = 16 * 128;      // 2048 floats per row
constexpr int ROWV4   = HD / 4;        // 512 float4 per row
constexpr int TOTAL   = T_FULL * ROWV4; // 7,864,320 f4 per K/V plane

constexpr int NBLK = 2048;
constexpr int BS   = 256;

// Native clang vector type: __builtin_nontemporal_* requires it.
typedef float f4 __attribute__((ext_vector_type(4)));

__global__ __launch_bounds__(BS) void kv_linearize_kernel(
    const f4* __restrict__ sink_k, const f4* __restrict__ sink_v,
    const f4* __restrict__ local_k, const f4* __restrict__ local_v,
    const f4* __restrict__ new_k, const f4* __restrict__ new_v,
    const int* __restrict__ write_idx_p,
    f4* __restrict__ out)
{
    // write_idx is a runtime scalar; normalize into [0, LOCAL)
    int wi = write_idx_p[0] % LOCAL;
    if (wi < 0) wi += LOCAL;
    int nwi = wi + NEW_LEN;            // new_write_idx
    if (nwi >= LOCAL) nwi -= LOCAL;

    const int stride = NBLK * BS;
    for (int i = blockIdx.x * BS + threadIdx.x; i < TOTAL; i += stride) {
        const int t = i >> 9;          // row (wave-uniform: 64 lanes in-row)
        const int c = i & (ROWV4 - 1); // f4 column within row

        const f4* __restrict__ srcK;
        const f4* __restrict__ srcV;
        if (t < SINK) {
            srcK = sink_k + (size_t)t * ROWV4;
            srcV = sink_v + (size_t)t * ROWV4;
        } else {
            int r0 = (t - SINK) + nwi;     // roll by -new_write_idx
            if (r0 >= LOCAL) r0 -= LOCAL;
            int d = r0 - wi;               // distance into written window
            if (d < 0) d += LOCAL;
            if (d < NEW_LEN) {
                srcK = new_k + (size_t)d * ROWV4;
                srcV = new_v + (size_t)d * ROWV4;
            } else {
                srcK = local_k + (size_t)r0 * ROWV4;
                srcV = local_v + (size_t)r0 * ROWV4;
            }
        }

        f4 vk = __builtin_nontemporal_load(srcK + c);
        f4 vv = __builtin_nontemporal_load(srcV + c);
        __builtin_nontemporal_store(vk, out + i);
        __builtin_nontemporal_store(vv, out + (size_t)TOTAL + i);
    }
}

extern "C" void kernel_launch(void* const* d_in, const int* in_sizes, int n_in,
                              void* d_out, int out_size, void* d_ws, size_t ws_size,
                              hipStream_t stream) {
    const f4* sink_k  = (const f4*)d_in[0];
    const f4* sink_v  = (const f4*)d_in[1];
    const f4* local_k = (const f4*)d_in[2];
    const f4* local_v = (const f4*)d_in[3];
    const f4* new_k   = (const f4*)d_in[4];
    const f4* new_v   = (const f4*)d_in[5];
    const int*  widx  = (const int*)d_in[6];
    f4*         out   = (f4*)d_out;

    kv_linearize_kernel<<<dim3(NBLK), dim3(BS), 0, stream>>>(
        sink_k, sink_v, local_k, local_v, new_k, new_v, widx, out);
}

// Round 6
// 84.035 us; speedup vs baseline: 1.0965x; 1.0809x over previous
//
#include <hip/hip_runtime.h>

// StaticKVCache steady-state step: ring write + roll + concat as a pure
// permutation-copy gather. One block per output row t; the block handles BOTH
// K and V (identical row mapping) -> 2 independent load/store chains per
// thread for memory-level parallelism. Nontemporal hints: every byte is
// touched exactly once, so cache retention is pure pollution.
//
// Shape notes (empirically settled this session):
//  - RPB=4 per-thread batching: -8% (R4). Persistent grid-stride 2048 blocks:
//    -7% (R5). TLP at 15360x512 already saturates HBM; extra per-thread ILP
//    or loop overhead only hurts. Keep the shallow 1-row/block shape.
//
// Row mapping for output row t (0..15359):
//   t < SINK          -> sink row t
//   else tt = t-SINK  -> ring row r0 = (tt + new_write_idx) % LOCAL
//       d = (r0 - write_idx) mod LOCAL
//       d < NEW_LEN   -> new row d          (freshly written slot)
//       else          -> local row r0       (untouched ring slot)

constexpr int SINK    = 3 * 1024;    // 3072
constexpr int LOCAL   = 12 * 1024;   // 12288
constexpr int NEW_LEN = 1024;
constexpr int T_FULL  = SINK + LOCAL;  // 15360
constexpr int HD      = 16 * 128;      // 2048 floats per row
constexpr int ROWV4   = HD / 4;        // 512 float4 per row

// Native clang vector type: __builtin_nontemporal_* requires it
// (HIP_vector_type float4 is a struct and is rejected).
typedef float f4 __attribute__((ext_vector_type(4)));

__global__ __launch_bounds__(ROWV4) void kv_linearize_kernel(
    const f4* __restrict__ sink_k, const f4* __restrict__ sink_v,
    const f4* __restrict__ local_k, const f4* __restrict__ local_v,
    const f4* __restrict__ new_k, const f4* __restrict__ new_v,
    const int* __restrict__ write_idx_p,
    f4* __restrict__ out)
{
    const int t = blockIdx.x;   // 0..T_FULL-1 (linearized seq position)
    const int c = threadIdx.x;  // 0..ROWV4-1 (float4 column within row)

    const f4* __restrict__ srcK;
    const f4* __restrict__ srcV;

    if (t < SINK) {
        srcK = sink_k + (size_t)t * ROWV4;
        srcV = sink_v + (size_t)t * ROWV4;
    } else {
        // write_idx is a runtime scalar; normalize into [0, LOCAL)
        int wi = write_idx_p[0] % LOCAL;
        if (wi < 0) wi += LOCAL;
        int nwi = wi + NEW_LEN;            // new_write_idx
        if (nwi >= LOCAL) nwi -= LOCAL;

        int r0 = (t - SINK) + nwi;         // roll by -new_write_idx
        if (r0 >= LOCAL) r0 -= LOCAL;

        int d = r0 - wi;                   // distance into the written window
        if (d < 0) d += LOCAL;

        if (d < NEW_LEN) {
            srcK = new_k + (size_t)d * ROWV4;
            srcV = new_v + (size_t)d * ROWV4;
        } else {
            srcK = local_k + (size_t)r0 * ROWV4;
            srcV = local_v + (size_t)r0 * ROWV4;
        }
    }

    // Two independent load->store chains (K and V) per thread: 2x MLP.
    f4 vk = __builtin_nontemporal_load(srcK + c);
    f4 vv = __builtin_nontemporal_load(srcV + c);
    __builtin_nontemporal_store(vk, out + (size_t)t * ROWV4 + c);
    __builtin_nontemporal_store(vv, out + ((size_t)T_FULL + t) * ROWV4 + c);
}

extern "C" void kernel_launch(void* const* d_in, const int* in_sizes, int n_in,
                              void* d_out, int out_size, void* d_ws, size_t ws_size,
                              hipStream_t stream) {
    const f4* sink_k  = (const f4*)d_in[0];
    const f4* sink_v  = (const f4*)d_in[1];
    const f4* local_k = (const f4*)d_in[2];
    const f4* local_v = (const f4*)d_in[3];
    const f4* new_k   = (const f4*)d_in[4];
    const f4* new_v   = (const f4*)d_in[5];
    const int*  widx  = (const int*)d_in[6];
    f4*         out   = (f4*)d_out;

    dim3 grid(T_FULL);
    dim3 block(ROWV4);
    kv_linearize_kernel<<<grid, block, 0, stream>>>(
        sink_k, sink_v, local_k, local_v, new_k, new_v, widx, out);
}